// Round 1
// baseline (251.511 us; speedup 1.0000x reference)
//
#include <hip/hip_runtime.h>
#include <hip/hip_bf16.h>

// diag(triggers * mask) for N=8192.
// Output: 8192x8192 fp32, zero except out[i*(N+1)] = triggers[i]*mask[i].
// Harness poisons d_out each call -> must zero all 256 MiB every launch.
// Strategy: hipMemsetAsync (fast runtime zero-fill, capture-safe) + tiny
// diagonal-writer kernel (8192 scattered stores, negligible).

#define N 8192

__global__ void diag_write_kernel(const float* __restrict__ triggers,
                                  const int* __restrict__ mask,
                                  float* __restrict__ out) {
    int i = blockIdx.x * blockDim.x + threadIdx.x;
    if (i < N) {
        size_t idx = (size_t)i * (size_t)(N + 1);  // row i, col i
        out[idx] = triggers[i] * (float)mask[i];
    }
}

extern "C" void kernel_launch(void* const* d_in, const int* in_sizes, int n_in,
                              void* d_out, int out_size, void* d_ws, size_t ws_size,
                              hipStream_t stream) {
    const float* triggers = (const float*)d_in[0];
    const int*   mask     = (const int*)d_in[1];
    float*       out      = (float*)d_out;

    // Zero the whole 256 MiB output (poisoned to 0xAA before each call).
    hipMemsetAsync(out, 0, (size_t)N * (size_t)N * sizeof(float), stream);

    // Write the 8192 diagonal elements.
    diag_write_kernel<<<(N + 255) / 256, 256, 0, stream>>>(triggers, mask, out);
}